// Round 1
// 233.846 us; speedup vs baseline: 1.1001x; 1.1001x over previous
//
#include <hip/hip_runtime.h>
#include <hip/hip_bf16.h>
#include <cstdint>
#include <cstddef>

#define NB   32
#define CIN  128
#define HWP  3136          // 56*56
#define KOC  256
#define NRS  9
#define PSTR 58            // padded row stride (w: -1..56)
#define PROW 3364          // 58*58 padded rows per (n,ck)
#define WIN  256           // halo window rows staged per ck
#define WINB (WIN * 64)    // bytes per LDS buffer = 16384

typedef __attribute__((ext_vector_type(8))) short  short8;
typedef __attribute__((ext_vector_type(4))) short  short4v;
typedef __attribute__((ext_vector_type(4))) float  float4v;

__device__ __forceinline__ unsigned short f2bf(float f) {
    union { float f; unsigned int u; } v; v.f = f;
    unsigned int u = v.u;
    u = u + 0x7fffu + ((u >> 16) & 1u);   // RNE
    return (unsigned short)(u >> 16);
}

// ---------------------------------------------------------------------------
// Fused prep kernel:
//   blocks [0, 1152):      W (OIHW fp32) -> wt2 MFMA-fragment order
//                          [rs][ck][ot][wm][i][quad][lr][e]
//   blocks [1152, 2816):   x NCHW fp32 -> xt[n][ck][p'][32c] bf16 halo layout
// The two jobs touch disjoint outputs; fusing overlaps them and removes one
// launch. Guard rows of xt are pre-zeroed by hipMemsetAsync (stream-ordered
// before this kernel).
// ---------------------------------------------------------------------------
__global__ __launch_bounds__(256) void prep_kernel(const float* __restrict__ W,
                                                   unsigned short* __restrict__ wt2,
                                                   const float* __restrict__ x,
                                                   unsigned short* __restrict__ xt) {
    __shared__ unsigned short lds[32 * 260];
    int blk = blockIdx.x;
    int t   = threadIdx.x;

    if (blk < 1152) {
        // ---- wt2 part ----
        int idx = blk * 256 + t;
        int e    = idx & 7;
        int lr   = (idx >> 3) & 15;
        int quad = (idx >> 7) & 3;
        int i    = (idx >> 9) & 3;
        int wm   = (idx >> 11) & 1;
        int ot   = (idx >> 12) & 1;
        int ck   = (idx >> 13) & 3;
        int rs   = idx >> 15;
        int oc = ot * 128 + wm * 64 + i * 16 + lr;
        int c  = ck * 32 + quad * 8 + e;
        wt2[idx] = f2bf(W[((size_t)oc * CIN + c) * NRS + rs]);
        return;
    }

    // ---- xpose part ----
    int b    = blk - 1152;
    int tile = b % 13;
    int ck   = (b / 13) & 3;
    int n    = b / 52;
    int hw0  = tile * 256;
    int wv   = t >> 6;
    int lane = t & 63;

    const float* src = x + ((size_t)(n * CIN + ck * 32)) * HWP;
    #pragma unroll
    for (int pass = 0; pass < 8; ++pass) {
        int c  = pass * 4 + wv;
        int hw = hw0 + lane * 4;
        if (hw < HWP) {
            float4v v = *(const float4v*)(src + (size_t)c * HWP + hw);
            short4v s4;
            #pragma unroll
            for (int k = 0; k < 4; ++k) s4[k] = (short)f2bf(v[k]);
            *(short4v*)(&lds[c * 260 + lane * 4]) = s4;
        }
    }
    __syncthreads();

    int sub = t & 3;
    int hwl = t >> 2;
    unsigned short* dst = xt + ((size_t)(n * 4 + ck)) * PROW * 32;
    #pragma unroll
    for (int pass = 0; pass < 4; ++pass) {
        int hl = pass * 64 + hwl;
        int hw = hw0 + hl;
        if (hw < HWP) {
            short8 v;
            #pragma unroll
            for (int j = 0; j < 8; ++j)
                v[j] = (short)lds[(sub * 8 + j) * 260 + hl];
            int pr = hw + 59 + 2 * (hw / 56);
            *(short8*)(dst + (size_t)pr * 32 + sub * 8) = v;
        }
    }
}

// ---------------------------------------------------------------------------
// Stage one 256-row halo window (16 KB) into LDS via async global_load_lds.
// XOR swizzle: LDS slot (r,q) holds global 16B-chunk (r, q ^ ((r>>1)&3)).
// Per wave: 4 instructions; 4 waves cover all 1024 slots.
// ---------------------------------------------------------------------------
__device__ __forceinline__ void stage_window(const unsigned short* gwin,
                                             unsigned short* lwin,
                                             int wv, int lane) {
    #pragma unroll
    for (int it = 0; it < 4; ++it) {
        int blk = it * 4 + wv;             // wave-chunk 0..15 (wave-uniform)
        int s   = blk * 64 + lane;         // slot 0..1023
        int r   = s >> 2;
        int q   = s & 3;
        int qs  = q ^ ((r >> 1) & 3);
        const char* g = (const char*)gwin + r * 64 + qs * 16;
        char*       l = (char*)lwin + blk * 1024;   // uniform base; lane*16 implicit
        __builtin_amdgcn_global_load_lds(
            (const __attribute__((address_space(1))) void*)g,
            (__attribute__((address_space(3))) void*)l, 16, 0, 0);
    }
}

__device__ __forceinline__ short8 ldb(const char* lb, int r, int quad) {
    int q = quad ^ ((r >> 1) & 3);
    return *(const short8*)(lb + r * 64 + q * 16);
}

// ---------------------------------------------------------------------------
// Implicit GEMM with per-ck halo-window LDS staging (B reused across all 9
// filter taps). 128 oc x 128 px per block, 4 waves (2x2), wave tile 64x64 via
// 4x4 mfma_f32_16x16x32_bf16. 4 barriers per block.
//
// Occupancy-tuned: A (global, L2-resident wt2, ~200-600 cyc) keeps a register
// ping-pong; B (LDS, ~120 cyc) is single-buffered. Live set ~= 64 acc +
// 16 afc + 16 afn + 16 bf + ~12 addr <= 128 unified regs ->
// __launch_bounds__(256, 4) pins 4 waves/SIMD (4 blocks/CU; LDS allows 5).
// Previous version double-buffered both A and B (~160+ unified regs -> only
// 2-3 waves/SIMD; OccupancyPercent 15.7%, MfmaUtil 19%).
// ---------------------------------------------------------------------------
__global__ __launch_bounds__(256, 4) void gemm_kernel(const unsigned short* __restrict__ xt,
                                                      const unsigned short* __restrict__ wt2,
                                                      const float* __restrict__ bias,
                                                      float* __restrict__ out) {
    __shared__ unsigned short b_lds[2 * WIN * 32];   // 32 KB, double-buffered

    int bx  = blockIdx.x;                 // 25 pt x 32 n x 2 ot = 1600
    int ot  = bx & 1;
    int n   = (bx >> 1) & 31;
    int pt  = bx >> 6;
    int oc0 = ot * 128;
    int p0  = pt * 128;

    int t    = threadIdx.x;
    int wv   = t >> 6;
    int lane = t & 63;
    int lr   = lane & 15;
    int quad = lane >> 4;
    int wm   = wv >> 1;
    int wn   = wv & 1;

    int prbase = p0 + 2 * (p0 / 56);      // = pr(p0) - 59, >= 0

    // per-j window row of the center tap (shift 0); clamped for tail tile
    int rb[4];
    #pragma unroll
    for (int j = 0; j < 4; ++j) {
        int hw  = p0 + wn * 64 + j * 16 + lr;
        int hwc = hw < HWP ? hw : (HWP - 1);
        rb[j] = hwc + 59 + 2 * (hwc / 56) - prbase;   // in [59, 252)
    }

    const unsigned short* xb = xt + (size_t)n * 4 * PROW * 32;

    float4v acc[4][4];
    #pragma unroll
    for (int i = 0; i < 4; ++i)
        #pragma unroll
        for (int j = 0; j < 4; ++j)
            acc[i][j] = (float4v){0.f, 0.f, 0.f, 0.f};

    // A running pointer: (rs,ck) slab = ((rs*4+ck)*2+ot)*4096 + wm*2048 + lane*8
    const unsigned short* ap = wt2 + (ot * 4096 + wm * 2048 + lane * 8);
    short8 afc[4];
    #pragma unroll
    for (int i = 0; i < 4; ++i) afc[i] = *(const short8*)(ap + i * 512);

    // prologue: stage ck=0 window into buffer 0
    stage_window(xb + (size_t)prbase * 32, b_lds, wv, lane);

    const int SH[9] = {-59, -58, -57, -1, 0, 1, 57, 58, 59};

    for (int ck = 0; ck < 4; ++ck) {
        __syncthreads();    // drains this wave's staging of buf[ck&1]
        if (ck < 3)
            stage_window(xb + (size_t)(ck + 1) * (PROW * 32) + (size_t)prbase * 32,
                         b_lds + ((ck + 1) & 1) * (WIN * 32), wv, lane);
        const char* lb = (const char*)b_lds + (ck & 1) * WINB;

        #pragma unroll
        for (int rs = 0; rs < 9; ++rs) {
            // prefetch next step's A (wraps to next ck; last wrap reads valid junk)
            ap += (rs == 8) ? -253952 : 32768;
            short8 afn[4];
            #pragma unroll
            for (int i = 0; i < 4; ++i) afn[i] = *(const short8*)(ap + i * 512);
            // B for THIS step, single-buffered from LDS (latency ~120 cyc,
            // covered by the A-issue + read-issue stream + TLP)
            short8 bf[4];
            #pragma unroll
            for (int j = 0; j < 4; ++j) bf[j] = ldb(lb, rb[j] + SH[rs], quad);
            #pragma unroll
            for (int i = 0; i < 4; ++i)
                #pragma unroll
                for (int j = 0; j < 4; ++j)
                    acc[i][j] = __builtin_amdgcn_mfma_f32_16x16x32_bf16(
                        afc[i], bf[j], acc[i][j], 0, 0, 0);
            #pragma unroll
            for (int i = 0; i < 4; ++i) afc[i] = afn[i];
        }
    }

    // epilogue: D row = oc (quad*4+reg), col = pixel (lane&15)
    float* orow = out + (size_t)n * KOC * HWP;
    #pragma unroll
    for (int i = 0; i < 4; ++i) {
        #pragma unroll
        for (int r = 0; r < 4; ++r) {
            int oc = oc0 + wm * 64 + i * 16 + quad * 4 + r;
            float bi = bias[oc];
            #pragma unroll
            for (int j = 0; j < 4; ++j) {
                int hw = p0 + wn * 64 + j * 16 + lr;
                if (hw < HWP)
                    orow[(size_t)oc * HWP + hw] = acc[i][j][r] + bi;
            }
        }
    }
}

// ---------------------------------------------------------------------------
// Safety fallback if ws is too small: naive direct conv (exact fp32).
// ---------------------------------------------------------------------------
__global__ void naive_kernel(const float* __restrict__ x, const float* __restrict__ W,
                             const float* __restrict__ b, float* __restrict__ out) {
    size_t idx = (size_t)blockIdx.x * 256 + threadIdx.x;
    if (idx >= (size_t)NB * KOC * HWP) return;
    int w0 = (int)(idx % 56);
    int h0 = (int)((idx / 56) % 56);
    int k  = (int)((idx / HWP) % KOC);
    int n  = (int)(idx / ((size_t)HWP * KOC));
    float acc = b[k];
    for (int c = 0; c < CIN; ++c) {
        const float* xr = x + ((size_t)n * CIN + c) * HWP;
        const float* wr = W + ((size_t)k * CIN + c) * NRS;
        for (int r = 0; r < 3; ++r) {
            int h = h0 + r - 1;
            if ((unsigned)h >= 56u) continue;
            for (int s = 0; s < 3; ++s) {
                int w = w0 + s - 1;
                if ((unsigned)w >= 56u) continue;
                acc += xr[h * 56 + w] * wr[r * 3 + s];
            }
        }
    }
    out[idx] = acc;
}

extern "C" void kernel_launch(void* const* d_in, const int* in_sizes, int n_in,
                              void* d_out, int out_size, void* d_ws, size_t ws_size,
                              hipStream_t stream) {
    const float* x  = (const float*)d_in[0];
    const float* W  = (const float*)d_in[1];
    const float* b  = (const float*)d_in[2];
    float* out = (float*)d_out;

    const size_t wt_elems = (size_t)NRS * 4 * 2 * 2 * 4 * 4 * 16 * 8;   // 294912
    const size_t xt_elems = (size_t)NB * 4 * PROW * 32 + WIN * 32;      // + staging guard
    const size_t need = (wt_elems + xt_elems) * sizeof(unsigned short); // ~28.2 MB

    if (ws_size < need) {
        size_t total = (size_t)NB * KOC * HWP;
        naive_kernel<<<(unsigned)((total + 255) / 256), 256, 0, stream>>>(x, W, b, out);
        return;
    }

    unsigned short* wt2 = (unsigned short*)d_ws;
    unsigned short* xt  = wt2 + wt_elems;        // 16B-aligned

    hipMemsetAsync(xt, 0, xt_elems * sizeof(unsigned short), stream);
    prep_kernel<<<1152 + NB * 4 * 13, 256, 0, stream>>>(W, wt2, x, xt);
    gemm_kernel<<<1600, 256, 0, stream>>>(xt, wt2, b, out);
}

// Round 2
// 215.990 us; speedup vs baseline: 1.1911x; 1.0827x over previous
//
#include <hip/hip_runtime.h>
#include <hip/hip_bf16.h>
#include <cstdint>
#include <cstddef>

#define NB   32
#define CIN  128
#define HWP  3136          // 56*56
#define KOC  256
#define NRS  9
#define PSTR 58            // padded row stride (w: -1..56)
#define PROW 3364          // 58*58 padded rows per (n,ck)
#define WIN  256           // halo window rows staged per ck
#define WINB (WIN * 64)    // bytes per LDS buffer = 16384

typedef __attribute__((ext_vector_type(8))) short  short8;
typedef __attribute__((ext_vector_type(4))) short  short4v;
typedef __attribute__((ext_vector_type(4))) float  float4v;

__device__ __forceinline__ unsigned short f2bf(float f) {
    union { float f; unsigned int u; } v; v.f = f;
    unsigned int u = v.u;
    u = u + 0x7fffu + ((u >> 16) & 1u);   // RNE
    return (unsigned short)(u >> 16);
}

// ---------------------------------------------------------------------------
// Fused prep kernel, three independent jobs (disjoint outputs, no ordering):
//   blocks [0, 1152):      W (OIHW fp32) -> wt2 MFMA-fragment order
//                          [rs][ck][ot][wm][i][quad][lr][e]
//   blocks [1152, 2816):   x NCHW fp32 -> xt[n][ck][p'][32c] bf16 halo layout
//                          (interior rows only)
//   blocks [2816, 2930):   zero the 228 guard rows per (n,ck) slab
//                          (replaces the old 27.5 MB full-buffer memset:
//                          guards are only 1.87 MB = 6.8% of xt)
// ---------------------------------------------------------------------------
__global__ __launch_bounds__(256) void prep_kernel(const float* __restrict__ W,
                                                   unsigned short* __restrict__ wt2,
                                                   const float* __restrict__ x,
                                                   unsigned short* __restrict__ xt) {
    __shared__ unsigned short lds[32 * 260];
    int blk = blockIdx.x;
    int t   = threadIdx.x;

    if (blk < 1152) {
        // ---- wt2 part ----
        int idx = blk * 256 + t;
        int e    = idx & 7;
        int lr   = (idx >> 3) & 15;
        int quad = (idx >> 7) & 3;
        int i    = (idx >> 9) & 3;
        int wm   = (idx >> 11) & 1;
        int ot   = (idx >> 12) & 1;
        int ck   = (idx >> 13) & 3;
        int rs   = idx >> 15;
        int oc = ot * 128 + wm * 64 + i * 16 + lr;
        int c  = ck * 32 + quad * 8 + e;
        wt2[idx] = f2bf(W[((size_t)oc * CIN + c) * NRS + rs]);
        return;
    }

    if (blk >= 2816) {
        // ---- guard-zero part: 128 slabs x 228 guard rows, 64 B each ----
        int g = (blk - 2816) * 256 + t;            // 0 .. 29183 (exact)
        int slab = g / 228;
        int gi   = g - slab * 228;
        int row;
        if (gi < 59)       row = gi;                               // top halo
        else if (gi < 169) { int k = gi - 59;                      // seam gaps
                             row = 115 + 58 * (k >> 1) + (k & 1); }
        else               row = 3305 + (gi - 169);                // bottom halo
        unsigned short* gr = xt + (size_t)slab * (PROW * 32) + (size_t)row * 32;
        short8 z = (short8)0;
        *(short8*)(gr +  0) = z;
        *(short8*)(gr +  8) = z;
        *(short8*)(gr + 16) = z;
        *(short8*)(gr + 24) = z;
        return;
    }

    // ---- xpose part (interior rows) ----
    int b    = blk - 1152;
    int tile = b % 13;
    int ck   = (b / 13) & 3;
    int n    = b / 52;
    int hw0  = tile * 256;
    int wv   = t >> 6;
    int lane = t & 63;

    const float* src = x + ((size_t)(n * CIN + ck * 32)) * HWP;
    #pragma unroll
    for (int pass = 0; pass < 8; ++pass) {
        int c  = pass * 4 + wv;
        int hw = hw0 + lane * 4;
        if (hw < HWP) {
            float4v v = *(const float4v*)(src + (size_t)c * HWP + hw);
            short4v s4;
            #pragma unroll
            for (int k = 0; k < 4; ++k) s4[k] = (short)f2bf(v[k]);
            *(short4v*)(&lds[c * 260 + lane * 4]) = s4;
        }
    }
    __syncthreads();

    int sub = t & 3;
    int hwl = t >> 2;
    unsigned short* dst = xt + ((size_t)(n * 4 + ck)) * PROW * 32;
    #pragma unroll
    for (int pass = 0; pass < 4; ++pass) {
        int hl = pass * 64 + hwl;
        int hw = hw0 + hl;
        if (hw < HWP) {
            short8 v;
            #pragma unroll
            for (int j = 0; j < 8; ++j)
                v[j] = (short)lds[(sub * 8 + j) * 260 + hl];
            int pr = hw + 59 + 2 * (hw / 56);
            *(short8*)(dst + (size_t)pr * 32 + sub * 8) = v;
        }
    }
}

// ---------------------------------------------------------------------------
// Stage one 256-row halo window (16 KB) into LDS via async global_load_lds.
// XOR swizzle: LDS slot (r,q) holds global 16B-chunk (r, q ^ ((r>>1)&3)).
// Per wave: 4 instructions; 4 waves cover all 1024 slots.
// ---------------------------------------------------------------------------
__device__ __forceinline__ void stage_window(const unsigned short* gwin,
                                             unsigned short* lwin,
                                             int wv, int lane) {
    #pragma unroll
    for (int it = 0; it < 4; ++it) {
        int blk = it * 4 + wv;             // wave-chunk 0..15 (wave-uniform)
        int s   = blk * 64 + lane;         // slot 0..1023
        int r   = s >> 2;
        int q   = s & 3;
        int qs  = q ^ ((r >> 1) & 3);
        const char* g = (const char*)gwin + r * 64 + qs * 16;
        char*       l = (char*)lwin + blk * 1024;   // uniform base; lane*16 implicit
        __builtin_amdgcn_global_load_lds(
            (const __attribute__((address_space(1))) void*)g,
            (__attribute__((address_space(3))) void*)l, 16, 0, 0);
    }
}

__device__ __forceinline__ short8 ldb(const char* lb, int r, int quad) {
    int q = quad ^ ((r >> 1) & 3);
    return *(const short8*)(lb + r * 64 + q * 16);
}

// ---------------------------------------------------------------------------
// Implicit GEMM with per-ck halo-window LDS staging (B reused across all 9
// filter taps). 128 oc x 128 px per block, 4 waves (2x2), wave tile 64x64 via
// 4x4 mfma_f32_16x16x32_bf16. 4 barriers per block.
//
// Register budget for 4 waves/SIMD (<=128 unified regs, no spill):
//   acc 64 + afc 16 + afn 16 + bcur/bnext 8 + addressing ~15  ~= 119.
// A (global wt2, L2-resident, 200-600 cyc) keeps a full rs-step ping-pong;
// B (LDS, ~120 cyc) is pipelined two-fragments-deep inside the j loop (each
// ds_read covered by 4 MFMAs + 3 co-resident waves). The previous round
// buffered B as bf[4] (16 regs) which pushed the live set past 128 ->
// ~1.4 dwords/lane/step of scratch spill (WRITE_SIZE 100->182 MB).
// ---------------------------------------------------------------------------
__global__ __launch_bounds__(256, 4) void gemm_kernel(const unsigned short* __restrict__ xt,
                                                      const unsigned short* __restrict__ wt2,
                                                      const float* __restrict__ bias,
                                                      float* __restrict__ out) {
    __shared__ unsigned short b_lds[2 * WIN * 32];   // 32 KB, double-buffered

    int bx  = blockIdx.x;                 // 25 pt x 32 n x 2 ot = 1600
    int ot  = bx & 1;
    int n   = (bx >> 1) & 31;
    int pt  = bx >> 6;
    int oc0 = ot * 128;
    int p0  = pt * 128;

    int t    = threadIdx.x;
    int wv   = t >> 6;
    int lane = t & 63;
    int lr   = lane & 15;
    int quad = lane >> 4;
    int wm   = wv >> 1;
    int wn   = wv & 1;

    int prbase = p0 + 2 * (p0 / 56);      // = pr(p0) - 59, >= 0

    // per-j window row of the center tap (shift 0); clamped for tail tile
    int rb[4];
    #pragma unroll
    for (int j = 0; j < 4; ++j) {
        int hw  = p0 + wn * 64 + j * 16 + lr;
        int hwc = hw < HWP ? hw : (HWP - 1);
        rb[j] = hwc + 59 + 2 * (hwc / 56) - prbase;   // in [59, 252)
    }

    const unsigned short* xb = xt + (size_t)n * 4 * PROW * 32;

    float4v acc[4][4];
    #pragma unroll
    for (int i = 0; i < 4; ++i)
        #pragma unroll
        for (int j = 0; j < 4; ++j)
            acc[i][j] = (float4v){0.f, 0.f, 0.f, 0.f};

    // A running pointer: (rs,ck) slab = ((rs*4+ck)*2+ot)*4096 + wm*2048 + lane*8
    const unsigned short* ap = wt2 + (ot * 4096 + wm * 2048 + lane * 8);
    short8 afc[4];
    #pragma unroll
    for (int i = 0; i < 4; ++i) afc[i] = *(const short8*)(ap + i * 512);

    // prologue: stage ck=0 window into buffer 0
    stage_window(xb + (size_t)prbase * 32, b_lds, wv, lane);

    const int SH[9] = {-59, -58, -57, -1, 0, 1, 57, 58, 59};

    for (int ck = 0; ck < 4; ++ck) {
        __syncthreads();    // drains this wave's staging of buf[ck&1]
        if (ck < 3)
            stage_window(xb + (size_t)(ck + 1) * (PROW * 32) + (size_t)prbase * 32,
                         b_lds + ((ck + 1) & 1) * (WIN * 32), wv, lane);
        const char* lb = (const char*)b_lds + (ck & 1) * WINB;

        #pragma unroll
        for (int rs = 0; rs < 9; ++rs) {
            // prefetch next step's A (wraps to next ck; last wrap reads valid junk)
            ap += (rs == 8) ? -253952 : 32768;
            short8 afn[4];
            #pragma unroll
            for (int i = 0; i < 4; ++i) afn[i] = *(const short8*)(ap + i * 512);
            // B two-deep rotation within the step (keeps live B at 8 regs)
            short8 bcur = ldb(lb, rb[0] + SH[rs], quad);
            #pragma unroll
            for (int j = 0; j < 4; ++j) {
                short8 bnext;
                if (j < 3) bnext = ldb(lb, rb[j + 1] + SH[rs], quad);
                #pragma unroll
                for (int i = 0; i < 4; ++i)
                    acc[i][j] = __builtin_amdgcn_mfma_f32_16x16x32_bf16(
                        afc[i], bcur, acc[i][j], 0, 0, 0);
                if (j < 3) bcur = bnext;
            }
            #pragma unroll
            for (int i = 0; i < 4; ++i) afc[i] = afn[i];
        }
    }

    // epilogue: D row = oc (quad*4+reg), col = pixel (lane&15)
    float* orow = out + (size_t)n * KOC * HWP;
    #pragma unroll
    for (int i = 0; i < 4; ++i) {
        #pragma unroll
        for (int r = 0; r < 4; ++r) {
            int oc = oc0 + wm * 64 + i * 16 + quad * 4 + r;
            float bi = bias[oc];
            #pragma unroll
            for (int j = 0; j < 4; ++j) {
                int hw = p0 + wn * 64 + j * 16 + lr;
                if (hw < HWP)
                    orow[(size_t)oc * HWP + hw] = acc[i][j][r] + bi;
            }
        }
    }
}

// ---------------------------------------------------------------------------
// Safety fallback if ws is too small: naive direct conv (exact fp32).
// ---------------------------------------------------------------------------
__global__ void naive_kernel(const float* __restrict__ x, const float* __restrict__ W,
                             const float* __restrict__ b, float* __restrict__ out) {
    size_t idx = (size_t)blockIdx.x * 256 + threadIdx.x;
    if (idx >= (size_t)NB * KOC * HWP) return;
    int w0 = (int)(idx % 56);
    int h0 = (int)((idx / 56) % 56);
    int k  = (int)((idx / HWP) % KOC);
    int n  = (int)(idx / ((size_t)HWP * KOC));
    float acc = b[k];
    for (int c = 0; c < CIN; ++c) {
        const float* xr = x + ((size_t)n * CIN + c) * HWP;
        const float* wr = W + ((size_t)k * CIN + c) * NRS;
        for (int r = 0; r < 3; ++r) {
            int h = h0 + r - 1;
            if ((unsigned)h >= 56u) continue;
            for (int s = 0; s < 3; ++s) {
                int w = w0 + s - 1;
                if ((unsigned)w >= 56u) continue;
                acc += xr[h * 56 + w] * wr[r * 3 + s];
            }
        }
    }
    out[idx] = acc;
}

extern "C" void kernel_launch(void* const* d_in, const int* in_sizes, int n_in,
                              void* d_out, int out_size, void* d_ws, size_t ws_size,
                              hipStream_t stream) {
    const float* x  = (const float*)d_in[0];
    const float* W  = (const float*)d_in[1];
    const float* b  = (const float*)d_in[2];
    float* out = (float*)d_out;

    const size_t wt_elems = (size_t)NRS * 4 * 2 * 2 * 4 * 4 * 16 * 8;   // 294912
    const size_t xt_elems = (size_t)NB * 4 * PROW * 32 + WIN * 32;      // + staging guard
    const size_t need = (wt_elems + xt_elems) * sizeof(unsigned short); // ~28.2 MB

    if (ws_size < need) {
        size_t total = (size_t)NB * KOC * HWP;
        naive_kernel<<<(unsigned)((total + 255) / 256), 256, 0, stream>>>(x, W, b, out);
        return;
    }

    unsigned short* wt2 = (unsigned short*)d_ws;
    unsigned short* xt  = wt2 + wt_elems;        // 16B-aligned

    // prep zeroes only the 228 guard rows per slab (no full-buffer memset)
    prep_kernel<<<1152 + NB * 4 * 13 + 114, 256, 0, stream>>>(W, wt2, x, xt);
    gemm_kernel<<<1600, 256, 0, stream>>>(xt, wt2, b, out);
}